// Round 1
// baseline (601.446 us; speedup 1.0000x reference)
//
#include <hip/hip_runtime.h>
#include <hip/hip_fp16.h>
#include <cmath>

#define NH 128
#define HD 128
#define RR 512
#define DQ 1536
#define BB 32
#define LL 4096
#define NSPLIT 8
#define LCHUNK 512
#define LTILE 32
#define NITER 16
#define LOG2E 1.44269504088896340736f

typedef _Float16 f16;
typedef f16 f16x4 __attribute__((ext_vector_type(4)));
typedef f16 f16x8 __attribute__((ext_vector_type(8)));
typedef float f32x4 __attribute__((ext_vector_type(4)));

// ---------------- Kernel A: q = hidden @ Wq^T + bq  -> [32, 16384] fp32 ----------------
// 256 blocks x 64 cols. Wq staged transposed in LDS so compute reads are float4.
__global__ __launch_bounds__(256) void qproj_kernel(const float* __restrict__ hidden,
                                                    const float* __restrict__ Wq,
                                                    const float* __restrict__ bq,
                                                    float* __restrict__ q) {
    __shared__ float hid[32][132];   // pad 132: b128-aligned writes, 4-way-max read conflicts
    __shared__ float wqt[128][68];   // transposed [d][c]; 68*4=272B rows keep b128 reads aligned
    const int tid = threadIdx.x;
    const int blk = blockIdx.x;
    const int c0 = (tid & 15) * 4;
    const int rbase = (tid >> 4) * 2;
    float acc[2][4] = {};
    for (int dt = 0; dt < DQ; dt += 128) {
        __syncthreads();
#pragma unroll
        for (int j = 0; j < 4; ++j) {
            int i = j * 256 + tid;
            int b = i >> 5, d4 = (i & 31) * 4;
            *(f32x4*)&hid[b][d4] = *(const f32x4*)&hidden[(size_t)b * DQ + dt + d4];
        }
#pragma unroll
        for (int j = 0; j < 8; ++j) {
            int i = j * 256 + tid;
            int cr = i >> 5, d4 = (i & 31) * 4;
            f32x4 v = *(const f32x4*)&Wq[(size_t)(blk * 64 + cr) * DQ + dt + d4];
            wqt[d4 + 0][cr] = v.x; wqt[d4 + 1][cr] = v.y;
            wqt[d4 + 2][cr] = v.z; wqt[d4 + 3][cr] = v.w;
        }
        __syncthreads();
        for (int kk = 0; kk < 128; ++kk) {
            f32x4 w = *(const f32x4*)&wqt[kk][c0];
            float h0 = hid[rbase][kk], h1 = hid[rbase + 1][kk];
            acc[0][0] += w.x * h0; acc[0][1] += w.y * h0; acc[0][2] += w.z * h0; acc[0][3] += w.w * h0;
            acc[1][0] += w.x * h1; acc[1][1] += w.y * h1; acc[1][2] += w.z * h1; acc[1][3] += w.w * h1;
        }
    }
    const int col = blk * 64 + c0;
    f32x4 bias = *(const f32x4*)&bq[col];
#pragma unroll
    for (int i = 0; i < 2; ++i) {
        f32x4 o;
        o.x = acc[i][0] + bias.x; o.y = acc[i][1] + bias.y;
        o.z = acc[i][2] + bias.z; o.w = acc[i][3] + bias.w;
        *(f32x4*)&q[(size_t)(rbase + i) * (NH * HD) + col] = o;
    }
}

// ---------------- Kernel B: q_abs[b,h,r] = sum_k w_kc[h,k,r]*q[b,h,k] -> fp16 ----------------
// 256 blocks = (h, r-half of 256). fp32 compute, fp16 store.
__global__ __launch_bounds__(256) void qabs_kernel(const float* __restrict__ q,
                                                   const float* __restrict__ w_kc,
                                                   f16* __restrict__ qabs) {
    __shared__ float qh[32][132];
    __shared__ float wl[128][68];
    const int tid = threadIdx.x;
    const int h = blockIdx.x >> 1;
    const int r0 = (blockIdx.x & 1) * 256;
#pragma unroll
    for (int j = 0; j < 4; ++j) {
        int i = j * 256 + tid;
        int b = i >> 5, k4 = (i & 31) * 4;
        *(f32x4*)&qh[b][k4] = *(const f32x4*)&q[(size_t)b * (NH * HD) + h * HD + k4];
    }
    const int rg = tid & 15, bg = tid >> 4;
    for (int rt = 0; rt < 4; ++rt) {
        __syncthreads();
#pragma unroll
        for (int j = 0; j < 8; ++j) {
            int i = j * 256 + tid;
            int kk = i >> 4, r4 = (i & 15) * 4;
            *(f32x4*)&wl[kk][r4] =
                *(const f32x4*)&w_kc[((size_t)h * HD + kk) * RR + r0 + rt * 64 + r4];
        }
        __syncthreads();
        float acc[2][4] = {};
        for (int kk = 0; kk < 128; ++kk) {
            f32x4 w = *(const f32x4*)&wl[kk][rg * 4];
            float q0 = qh[bg * 2][kk], q1 = qh[bg * 2 + 1][kk];
            acc[0][0] += w.x * q0; acc[0][1] += w.y * q0; acc[0][2] += w.z * q0; acc[0][3] += w.w * q0;
            acc[1][0] += w.x * q1; acc[1][1] += w.y * q1; acc[1][2] += w.z * q1; acc[1][3] += w.w * q1;
        }
        const int r = r0 + rt * 64 + rg * 4;
#pragma unroll
        for (int i = 0; i < 2; ++i) {
            f16x4 o = {(f16)acc[i][0], (f16)acc[i][1], (f16)acc[i][2], (f16)acc[i][3]};
            *(f16x4*)&qabs[((size_t)(bg * 2 + i) * NH + h) * RR + r] = o;
        }
    }
}

// ---------------- Kernel C: fused flash attention over latent KV ----------------
// grid 256 = (b, s): block = 8 waves x 16 heads = all 128 heads; L-chunk of 512, tiles of 32.
// S^T MFMA (m=l, n=h) so softmax stats are per-lane (h = lane&15); ctx^T (m=r, n=h).
__global__ __launch_bounds__(512, 2) void attn_kernel(const float* __restrict__ ckv,
                                                      const f16* __restrict__ qabs,
                                                      f16* __restrict__ part,
                                                      float* __restrict__ stats) {
    __shared__ f16 kv_lr[LTILE][520];   // [l][r], pad 8: A-frag for scores (k=r contiguous)
    __shared__ f16 kv_rl[RR][40];       // [r][l], pad 8: A-frag for ctx   (k=l contiguous)
    __shared__ f16 p_lds[8][16][40];    // per-wave P round-trip C-layout -> B-layout
    const int tid = threadIdx.x;
    const int lane = tid & 63;
    const int wave = tid >> 6;
    const int lh = lane & 15;
    const int quad = lane >> 4;
    const int b = blockIdx.x >> 3;
    const int s = blockIdx.x & 7;
    const int head = wave * 16 + lh;

    f16x8 qf[16];   // B-operand fragments: B[k=r][n=h], k = rc*32 + quad*8 + j
#pragma unroll
    for (int rc = 0; rc < 16; ++rc)
        qf[rc] = *(const f16x8*)&qabs[((size_t)b * NH + head) * RR + rc * 32 + quad * 8];

    f32x4 acc[32];   // ctx^T tiles: D[m=r (32 tiles of 16)][n=h]
#pragma unroll
    for (int rt = 0; rt < 32; ++rt) acc[rt] = f32x4{0.f, 0.f, 0.f, 0.f};
    float m_run = -INFINITY, l_run = 0.0f;

    const f32x4* src = (const f32x4*)(ckv + ((size_t)b * LL + s * LCHUNK) * RR);

    for (int it = 0; it < NITER; ++it) {
        const f32x4* tsrc = src + (size_t)it * (LTILE * RR / 4);
#pragma unroll
        for (int j = 0; j < 8; ++j) {
            int idx = j * 512 + tid;               // coalesced: 8 KB contiguous per j
            f32x4 v = tsrc[idx];
            int l = idx >> 7, r4 = (idx & 127) * 4;
            f16 h0 = (f16)v.x, h1 = (f16)v.y, h2 = (f16)v.z, h3 = (f16)v.w;
            f16x4 pk = {h0, h1, h2, h3};
            *(f16x4*)&kv_lr[l][r4] = pk;
            kv_rl[r4 + 0][l] = h0;
            kv_rl[r4 + 1][l] = h1;
            kv_rl[r4 + 2][l] = h2;
            kv_rl[r4 + 3][l] = h3;
        }
        __syncthreads();
        // scores S^T [32 l x 16 h] for this wave's heads
        f32x4 sc[2];
#pragma unroll
        for (int lt = 0; lt < 2; ++lt) {
            f32x4 s4 = f32x4{0.f, 0.f, 0.f, 0.f};
#pragma unroll
            for (int rc = 0; rc < 16; ++rc) {
                f16x8 a = *(const f16x8*)&kv_lr[lt * 16 + lh][rc * 32 + quad * 8];
                s4 = __builtin_amdgcn_mfma_f32_16x16x32_f16(a, qf[rc], s4, 0, 0, 0);
            }
            sc[lt] = s4;
        }
        // online softmax: rows = l (quad*4+reg), col = h = lane&15
        float tmax = fmaxf(fmaxf(fmaxf(sc[0].x, sc[0].y), fmaxf(sc[0].z, sc[0].w)),
                           fmaxf(fmaxf(sc[1].x, sc[1].y), fmaxf(sc[1].z, sc[1].w)));
        tmax = fmaxf(tmax, __shfl_xor(tmax, 16, 64));
        tmax = fmaxf(tmax, __shfl_xor(tmax, 32, 64));
        float new_m = fmaxf(m_run, tmax);
        float alpha = exp2f((m_run - new_m) * LOG2E);   // first iter: exp2(-inf) = 0
        float p0 = exp2f((sc[0].x - new_m) * LOG2E);
        float p1 = exp2f((sc[0].y - new_m) * LOG2E);
        float p2 = exp2f((sc[0].z - new_m) * LOG2E);
        float p3 = exp2f((sc[0].w - new_m) * LOG2E);
        float p4 = exp2f((sc[1].x - new_m) * LOG2E);
        float p5 = exp2f((sc[1].y - new_m) * LOG2E);
        float p6 = exp2f((sc[1].z - new_m) * LOG2E);
        float p7 = exp2f((sc[1].w - new_m) * LOG2E);
        f16x4 pk0 = {(f16)p0, (f16)p1, (f16)p2, (f16)p3};
        f16x4 pk1 = {(f16)p4, (f16)p5, (f16)p6, (f16)p7};
        *(f16x4*)&p_lds[wave][lh][quad * 4] = pk0;
        *(f16x4*)&p_lds[wave][lh][16 + quad * 4] = pk1;
        float psum = p0 + p1 + p2 + p3 + p4 + p5 + p6 + p7;
        psum += __shfl_xor(psum, 16, 64);
        psum += __shfl_xor(psum, 32, 64);
        l_run = l_run * alpha + psum;
        m_run = new_m;
        // ctx^T accumulate: A = kv_rl fragment, B = P from p_lds
        f16x8 pb = *(const f16x8*)&p_lds[wave][lh][quad * 8];
#pragma unroll
        for (int rt = 0; rt < 32; ++rt) {
            f16x8 a = *(const f16x8*)&kv_rl[rt * 16 + lh][quad * 8];
            f32x4 c = acc[rt];
            c.x *= alpha; c.y *= alpha; c.z *= alpha; c.w *= alpha;
            acc[rt] = __builtin_amdgcn_mfma_f32_16x16x32_f16(a, pb, c, 0, 0, 0);
        }
        __syncthreads();   // protect kv tiles before next stage
    }
    // normalized partial ctx (fp16) + per-head stats
    float inv_l = 1.0f / l_run;
    size_t base = (((size_t)b * NSPLIT + s) * NH + head) * RR;
#pragma unroll
    for (int rt = 0; rt < 32; ++rt) {
        f16x4 o = {(f16)(acc[rt].x * inv_l), (f16)(acc[rt].y * inv_l),
                   (f16)(acc[rt].z * inv_l), (f16)(acc[rt].w * inv_l)};
        *(f16x4*)&part[base + rt * 16 + quad * 4] = o;
    }
    if (quad == 0) {
        size_t sb = (((size_t)b * NSPLIT + s) * NH + head) * 2;
        stats[sb] = m_run;
        stats[sb + 1] = l_run;
    }
}

// ---------------- Kernel E: combine L-splits -> ctx [32,128,512] fp32 ----------------
__global__ __launch_bounds__(128) void combine_kernel(const f16* __restrict__ part,
                                                      const float* __restrict__ stats,
                                                      float* __restrict__ ctx) {
    const int blk = blockIdx.x;    // b*128 + h
    const int b = blk >> 7, h = blk & 127;
    const int tid = threadIdx.x;
    float m[NSPLIT], l[NSPLIT];
    float M = -INFINITY;
#pragma unroll
    for (int s = 0; s < NSPLIT; ++s) {
        size_t sb = (((size_t)b * NSPLIT + s) * NH + h) * 2;
        m[s] = stats[sb]; l[s] = stats[sb + 1];
        M = fmaxf(M, m[s]);
    }
    float w[NSPLIT], denom = 0.f;
#pragma unroll
    for (int s = 0; s < NSPLIT; ++s) {
        w[s] = l[s] * exp2f((m[s] - M) * LOG2E);
        denom += w[s];
    }
    float inv = 1.0f / denom;
    f32x4 sum = f32x4{0.f, 0.f, 0.f, 0.f};
#pragma unroll
    for (int s = 0; s < NSPLIT; ++s) {
        f16x4 v = *(const f16x4*)&part[(((size_t)b * NSPLIT + s) * NH + h) * RR + tid * 4];
        sum.x += w[s] * (float)v.x; sum.y += w[s] * (float)v.y;
        sum.z += w[s] * (float)v.z; sum.w += w[s] * (float)v.w;
    }
    sum.x *= inv; sum.y *= inv; sum.z *= inv; sum.w *= inv;
    *(f32x4*)&ctx[((size_t)b * NH + h) * RR + tid * 4] = sum;
}

// ---------------- Kernel D: out[b,h,k] = sum_r w_vc[h,k,r]*ctx[b,h,r] fp32 ----------------
__global__ __launch_bounds__(256) void outproj_kernel(const float* __restrict__ ctx,
                                                      const float* __restrict__ w_vc,
                                                      float* __restrict__ out) {
    __shared__ float cl[32][524];
    __shared__ float wl[64][69];
    const int tid = threadIdx.x;
    const int h = blockIdx.x >> 1;
    const int k0 = (blockIdx.x & 1) * 64;
#pragma unroll
    for (int j = 0; j < 16; ++j) {
        int i = j * 256 + tid;
        int bb = i >> 7, r4 = (i & 127) * 4;
        *(f32x4*)&cl[bb][r4] = *(const f32x4*)&ctx[((size_t)bb * NH + h) * RR + r4];
    }
    const int kg = tid & 15, bg = tid >> 4;
    float acc[2][4] = {};
    for (int rt = 0; rt < 8; ++rt) {
        __syncthreads();
#pragma unroll
        for (int j = 0; j < 4; ++j) {
            int i = j * 256 + tid;
            int kk = i >> 4, r4 = (i & 15) * 4;
            f32x4 v = *(const f32x4*)&w_vc[((size_t)h * HD + k0 + kk) * RR + rt * 64 + r4];
            wl[kk][r4 + 0] = v.x; wl[kk][r4 + 1] = v.y;
            wl[kk][r4 + 2] = v.z; wl[kk][r4 + 3] = v.w;
        }
        __syncthreads();
        for (int rr = 0; rr < 64; ++rr) {
            float c0 = cl[bg * 2][rt * 64 + rr], c1 = cl[bg * 2 + 1][rt * 64 + rr];
            float w0 = wl[kg * 4 + 0][rr], w1 = wl[kg * 4 + 1][rr];
            float w2 = wl[kg * 4 + 2][rr], w3 = wl[kg * 4 + 3][rr];
            acc[0][0] += w0 * c0; acc[0][1] += w1 * c0; acc[0][2] += w2 * c0; acc[0][3] += w3 * c0;
            acc[1][0] += w0 * c1; acc[1][1] += w1 * c1; acc[1][2] += w2 * c1; acc[1][3] += w3 * c1;
        }
    }
#pragma unroll
    for (int i = 0; i < 2; ++i) {
        f32x4 o = {acc[i][0], acc[i][1], acc[i][2], acc[i][3]};
        *(f32x4*)&out[(size_t)(bg * 2 + i) * (NH * HD) + h * HD + k0 + kg * 4] = o;
    }
}

extern "C" void kernel_launch(void* const* d_in, const int* in_sizes, int n_in,
                              void* d_out, int out_size, void* d_ws, size_t ws_size,
                              hipStream_t stream) {
    const float* hidden = (const float*)d_in[0];
    const float* ckv    = (const float*)d_in[1];
    const float* Wq     = (const float*)d_in[2];
    const float* bq     = (const float*)d_in[3];
    const float* w_kc   = (const float*)d_in[4];
    const float* w_vc   = (const float*)d_in[5];
    float* out = (float*)d_out;

    char* ws = (char*)d_ws;
    float* q     = (float*)(ws);                      // 32*16384*4      = 2 MB
    f16*   qabs  = (f16*)(ws + 2097152);              // 32*128*512*2    = 4 MB
    f16*   part  = (f16*)(ws + 6291456);              // 32*8*128*512*2  = 32 MB
    float* stats = (float*)(ws + 39845888);           // 32*8*128*2*4    = 256 KB
    float* ctx   = (float*)(ws + 40108032);           // 32*128*512*4    = 8 MB

    qproj_kernel<<<256, 256, 0, stream>>>(hidden, Wq, bq, q);
    qabs_kernel<<<256, 256, 0, stream>>>(q, w_kc, qabs);
    attn_kernel<<<256, 512, 0, stream>>>(ckv, qabs, part, stats);
    combine_kernel<<<BB * NH, 128, 0, stream>>>(part, stats, ctx);
    outproj_kernel<<<256, 256, 0, stream>>>(ctx, w_vc, out);
}

// Round 2
// 538.979 us; speedup vs baseline: 1.1159x; 1.1159x over previous
//
#include <hip/hip_runtime.h>
#include <hip/hip_fp16.h>
#include <cmath>

#define NH 128
#define HD 128
#define RR 512
#define DQ 1536
#define BB 32
#define LL 4096
#define NSPLIT 8
#define LCHUNK 512
#define LTILE 32
#define NITER 16
#define LOG2E 1.44269504088896340736f

typedef _Float16 f16;
typedef f16 f16x4 __attribute__((ext_vector_type(4)));
typedef f16 f16x8 __attribute__((ext_vector_type(8)));
typedef float f32x4 __attribute__((ext_vector_type(4)));

// ---------------- Kernel A: q16 = f16(hidden @ Wq^T + bq)  [32, 16384] ----------------
// MFMA 16x16x32 f16, K staged 128 at a time. Grid 256 x 512thr (8 waves, 1 tile each).
__global__ __launch_bounds__(512) void qproj_kernel(const float* __restrict__ hidden,
                                                    const float* __restrict__ Wq,
                                                    const float* __restrict__ bq,
                                                    f16* __restrict__ q16) {
    __shared__ f16 wq_s[64][136];   // [col][k] k-contiguous (B operand), pitch 272B (16B-aligned)
    __shared__ f16 hid_s[32][136];  // [b][k] (A operand)
    const int tid = threadIdx.x;
    const int lane = tid & 63, wave = tid >> 6;
    const int lh = lane & 15, quad = lane >> 4;
    const int mt = wave & 1, nt = wave >> 1;   // 2 m-tiles x 4 n-tiles = 8 waves
    const int col0 = blockIdx.x * 64;
    f32x4 acc = {0.f, 0.f, 0.f, 0.f};
    for (int dt = 0; dt < DQ; dt += 128) {
        __syncthreads();
        {   // stage Wq 64 rows x 128 k (rows are already [col][d] = [n][k])
            int r = tid >> 3, sg = (tid & 7) * 16;
            const float* src = &Wq[(size_t)(col0 + r) * DQ + dt + sg];
            f32x4 a0 = *(const f32x4*)&src[0], a1 = *(const f32x4*)&src[4];
            f32x4 a2 = *(const f32x4*)&src[8], a3 = *(const f32x4*)&src[12];
            f16x8 p0 = {(f16)a0.x,(f16)a0.y,(f16)a0.z,(f16)a0.w,(f16)a1.x,(f16)a1.y,(f16)a1.z,(f16)a1.w};
            f16x8 p1 = {(f16)a2.x,(f16)a2.y,(f16)a2.z,(f16)a2.w,(f16)a3.x,(f16)a3.y,(f16)a3.z,(f16)a3.w};
            *(f16x8*)&wq_s[r][sg] = p0;
            *(f16x8*)&wq_s[r][sg + 8] = p1;
        }
        {   // stage hidden 32 x 128
            int r = tid >> 4, sg = (tid & 15) * 8;
            const float* src = &hidden[(size_t)r * DQ + dt + sg];
            f32x4 b0 = *(const f32x4*)&src[0], b1 = *(const f32x4*)&src[4];
            f16x8 p = {(f16)b0.x,(f16)b0.y,(f16)b0.z,(f16)b0.w,(f16)b1.x,(f16)b1.y,(f16)b1.z,(f16)b1.w};
            *(f16x8*)&hid_s[r][sg] = p;
        }
        __syncthreads();
#pragma unroll
        for (int kk = 0; kk < 4; ++kk) {
            f16x8 a = *(const f16x8*)&hid_s[mt * 16 + lh][kk * 32 + quad * 8];
            f16x8 bb = *(const f16x8*)&wq_s[nt * 16 + lh][kk * 32 + quad * 8];
            acc = __builtin_amdgcn_mfma_f32_16x16x32_f16(a, bb, acc, 0, 0, 0);
        }
    }
    const int col = col0 + nt * 16 + lh;
    const float bias = bq[col];
#pragma unroll
    for (int i = 0; i < 4; ++i)
        q16[(size_t)(mt * 16 + quad * 4 + i) * (NH * HD) + col] = (f16)(acc[i] + bias);
}

// ---------------- Kernel B: qabs[b,h,r] = f16(sum_k w_kc[h,k,r]*q[b,h,k]) ----------------
// MFMA: m=b(32), n=r(256 half), k=128. Grid 256 = (h, r-half). w_kc transposed into LDS.
__global__ __launch_bounds__(512) void qabs_kernel(const f16* __restrict__ q16,
                                                   const float* __restrict__ w_kc,
                                                   f16* __restrict__ qabs) {
    __shared__ f16 wk_s[256][136];  // [r][k] k-contiguous (B operand)
    __shared__ f16 q_s[32][136];    // [b][k] (A operand)
    const int tid = threadIdx.x;
    const int lane = tid & 63, wave = tid >> 6;
    const int lh = lane & 15, quad = lane >> 4;
    const int h = blockIdx.x >> 1;
    const int rh = blockIdx.x & 1;
    {   // stage q tile 32 x 128 (already f16)
        int bb = tid >> 4, sg = (tid & 15) * 8;
        *(f16x8*)&q_s[bb][sg] = *(const f16x8*)&q16[(size_t)bb * (NH * HD) + h * HD + sg];
    }
    {   // stage w_kc transposed: thread owns 4k x 8r x 2 groups
        int k0 = (tid & 31) * 4, rb = tid >> 5;   // rb 0..15
#pragma unroll
        for (int j3 = 0; j3 < 2; ++j3) {
            int r0 = rb * 8 + j3 * 128;
            f16 ha[4][8];
#pragma unroll
            for (int ki = 0; ki < 4; ++ki) {
                const float* src = &w_kc[((size_t)h * HD + k0 + ki) * RR + rh * 256 + r0];
                f32x4 v0 = *(const f32x4*)&src[0], v1 = *(const f32x4*)&src[4];
                ha[ki][0]=(f16)v0.x; ha[ki][1]=(f16)v0.y; ha[ki][2]=(f16)v0.z; ha[ki][3]=(f16)v0.w;
                ha[ki][4]=(f16)v1.x; ha[ki][5]=(f16)v1.y; ha[ki][6]=(f16)v1.z; ha[ki][7]=(f16)v1.w;
            }
#pragma unroll
            for (int j = 0; j < 8; ++j) {
                f16x4 c = {ha[0][j], ha[1][j], ha[2][j], ha[3][j]};
                *(f16x4*)&wk_s[r0 + j][k0] = c;
            }
        }
    }
    __syncthreads();
    f32x4 acc[2][2] = {};
#pragma unroll
    for (int kt = 0; kt < 4; ++kt) {
        f16x8 a0 = *(const f16x8*)&q_s[lh][kt * 32 + quad * 8];
        f16x8 a1 = *(const f16x8*)&q_s[16 + lh][kt * 32 + quad * 8];
#pragma unroll
        for (int j = 0; j < 2; ++j) {
            f16x8 bb = *(const f16x8*)&wk_s[(wave * 2 + j) * 16 + lh][kt * 32 + quad * 8];
            acc[0][j] = __builtin_amdgcn_mfma_f32_16x16x32_f16(a0, bb, acc[0][j], 0, 0, 0);
            acc[1][j] = __builtin_amdgcn_mfma_f32_16x16x32_f16(a1, bb, acc[1][j], 0, 0, 0);
        }
    }
#pragma unroll
    for (int m = 0; m < 2; ++m)
#pragma unroll
        for (int j = 0; j < 2; ++j)
#pragma unroll
            for (int i = 0; i < 4; ++i) {
                int b = m * 16 + quad * 4 + i;
                int r = rh * 256 + (wave * 2 + j) * 16 + lh;
                qabs[((size_t)b * NH + h) * RR + r] = (f16)acc[m][j][i];
            }
}

// ---------------- Kernel C: fused flash attention over latent KV ----------------
// grid 256 = (b, s): 8 waves x 16 heads. Conflict-floor LDS transpose + register prefetch.
__global__ __launch_bounds__(512, 2) void attn_kernel(const float* __restrict__ ckv,
                                                      const f16* __restrict__ qabs,
                                                      f16* __restrict__ part,
                                                      float* __restrict__ stats) {
    __shared__ f16 kv_lr[LTILE][520];   // [l][r] (A for scores), pitch 1040B
    __shared__ f16 kv_rl[RR][36];       // [r][l] (A for ctx), pitch 72B -> bank-floor stores
    __shared__ f16 p_lds[8][16][40];    // per-wave P C->B layout round trip
    const int tid = threadIdx.x;
    const int lane = tid & 63, wave = tid >> 6;
    const int lh = lane & 15, quad = lane >> 4;
    const int b = blockIdx.x >> 3;
    const int s = blockIdx.x & 7;
    const int head = wave * 16 + lh;

    f16x8 qf[16];
#pragma unroll
    for (int rc = 0; rc < 16; ++rc)
        qf[rc] = *(const f16x8*)&qabs[((size_t)b * NH + head) * RR + rc * 32 + quad * 8];

    f32x4 acc[32];
#pragma unroll
    for (int rt = 0; rt < 32; ++rt) acc[rt] = f32x4{0.f, 0.f, 0.f, 0.f};
    float m_run = -INFINITY, l_run = 0.0f;

    const int rb = tid >> 3;            // 0..63 -> r block of 8
    const int l0 = (tid & 7) * 4;       // 0..28 -> 4 l rows
    const float* base = ckv + ((size_t)b * LL + s * LCHUNK) * RR;

    f32x4 pv[4][2];
#pragma unroll
    for (int li = 0; li < 4; ++li) {
        pv[li][0] = *(const f32x4*)&base[(size_t)(l0 + li) * RR + rb * 8];
        pv[li][1] = *(const f32x4*)&base[(size_t)(l0 + li) * RR + rb * 8 + 4];
    }

    for (int it = 0; it < NITER; ++it) {
        // convert prefetched tile, store both LDS layouts
        f16 ha[4][8];
#pragma unroll
        for (int li = 0; li < 4; ++li) {
            f32x4 v0 = pv[li][0], v1 = pv[li][1];
            ha[li][0]=(f16)v0.x; ha[li][1]=(f16)v0.y; ha[li][2]=(f16)v0.z; ha[li][3]=(f16)v0.w;
            ha[li][4]=(f16)v1.x; ha[li][5]=(f16)v1.y; ha[li][6]=(f16)v1.z; ha[li][7]=(f16)v1.w;
        }
#pragma unroll
        for (int li = 0; li < 4; ++li) {
            f16x8 row = {ha[li][0],ha[li][1],ha[li][2],ha[li][3],ha[li][4],ha[li][5],ha[li][6],ha[li][7]};
            *(f16x8*)&kv_lr[l0 + li][rb * 8] = row;
        }
#pragma unroll
        for (int j = 0; j < 8; ++j) {
            f16x4 c = {ha[0][j], ha[1][j], ha[2][j], ha[3][j]};
            *(f16x4*)&kv_rl[rb * 8 + j][l0] = c;
        }
        __syncthreads();
        if (it + 1 < NITER) {   // prefetch next tile; overlaps MFMA phase
            const float* nb = base + (size_t)(it + 1) * LTILE * RR;
#pragma unroll
            for (int li = 0; li < 4; ++li) {
                pv[li][0] = *(const f32x4*)&nb[(size_t)(l0 + li) * RR + rb * 8];
                pv[li][1] = *(const f32x4*)&nb[(size_t)(l0 + li) * RR + rb * 8 + 4];
            }
        }
        // scores S^T [32 l x 16 h]
        f32x4 sc[2];
#pragma unroll
        for (int lt = 0; lt < 2; ++lt) {
            f32x4 s4 = f32x4{0.f, 0.f, 0.f, 0.f};
#pragma unroll
            for (int rc = 0; rc < 16; ++rc) {
                f16x8 a = *(const f16x8*)&kv_lr[lt * 16 + lh][rc * 32 + quad * 8];
                s4 = __builtin_amdgcn_mfma_f32_16x16x32_f16(a, qf[rc], s4, 0, 0, 0);
            }
            sc[lt] = s4;
        }
        // online softmax (col = h = lane&15, rows l = quad*4+i)
        float tmax = fmaxf(fmaxf(fmaxf(sc[0].x, sc[0].y), fmaxf(sc[0].z, sc[0].w)),
                           fmaxf(fmaxf(sc[1].x, sc[1].y), fmaxf(sc[1].z, sc[1].w)));
        tmax = fmaxf(tmax, __shfl_xor(tmax, 16, 64));
        tmax = fmaxf(tmax, __shfl_xor(tmax, 32, 64));
        float new_m = fmaxf(m_run, tmax);
        float alpha = exp2f((m_run - new_m) * LOG2E);
        float p0 = exp2f((sc[0].x - new_m) * LOG2E);
        float p1 = exp2f((sc[0].y - new_m) * LOG2E);
        float p2 = exp2f((sc[0].z - new_m) * LOG2E);
        float p3 = exp2f((sc[0].w - new_m) * LOG2E);
        float p4 = exp2f((sc[1].x - new_m) * LOG2E);
        float p5 = exp2f((sc[1].y - new_m) * LOG2E);
        float p6 = exp2f((sc[1].z - new_m) * LOG2E);
        float p7 = exp2f((sc[1].w - new_m) * LOG2E);
        f16x4 pk0 = {(f16)p0, (f16)p1, (f16)p2, (f16)p3};
        f16x4 pk1 = {(f16)p4, (f16)p5, (f16)p6, (f16)p7};
        *(f16x4*)&p_lds[wave][lh][quad * 4] = pk0;
        *(f16x4*)&p_lds[wave][lh][16 + quad * 4] = pk1;
        float psum = p0 + p1 + p2 + p3 + p4 + p5 + p6 + p7;
        psum += __shfl_xor(psum, 16, 64);
        psum += __shfl_xor(psum, 32, 64);
        l_run = l_run * alpha + psum;
        m_run = new_m;
        f16x8 pb = *(const f16x8*)&p_lds[wave][lh][quad * 8];
#pragma unroll
        for (int rt = 0; rt < 32; ++rt) {
            f16x4 alo = *(const f16x4*)&kv_rl[rt * 16 + lh][quad * 8];
            f16x4 ahi = *(const f16x4*)&kv_rl[rt * 16 + lh][quad * 8 + 4];
            f16x8 a = __builtin_shufflevector(alo, ahi, 0, 1, 2, 3, 4, 5, 6, 7);
            f32x4 c = acc[rt];
            c.x *= alpha; c.y *= alpha; c.z *= alpha; c.w *= alpha;
            acc[rt] = __builtin_amdgcn_mfma_f32_16x16x32_f16(a, pb, c, 0, 0, 0);
        }
        __syncthreads();
    }
    // epilogue: per-wave LDS transpose (reuse kv_rl) -> coalesced 16B part stores
    float inv_l = 1.0f / l_run;
    f16* ebuf = (f16*)kv_rl + wave * (16 * 136);
    const int h2 = lane >> 2, off = (lane & 3) * 32;
    size_t obase = (((size_t)b * NSPLIT + s) * NH + wave * 16) * RR;
#pragma unroll
    for (int c = 0; c < 4; ++c) {
#pragma unroll
        for (int rt2 = 0; rt2 < 8; ++rt2) {
            f32x4 v = acc[c * 8 + rt2];
            f16x4 o = {(f16)(v.x * inv_l), (f16)(v.y * inv_l), (f16)(v.z * inv_l), (f16)(v.w * inv_l)};
            *(f16x4*)&ebuf[lh * 136 + rt2 * 16 + quad * 4] = o;
        }
#pragma unroll
        for (int k2 = 0; k2 < 4; ++k2) {
            f16x8 v = *(const f16x8*)&ebuf[h2 * 136 + off + k2 * 8];
            *(f16x8*)&part[obase + (size_t)h2 * RR + c * 128 + off + k2 * 8] = v;
        }
    }
    if (quad == 0) {
        size_t sb = (((size_t)b * NSPLIT + s) * NH + head) * 2;
        stats[sb] = m_run;
        stats[sb + 1] = l_run;
    }
}

// ---------------- Kernel E: combine L-splits -> ctx f16 [32,128,512] ----------------
__global__ __launch_bounds__(128) void combine_kernel(const f16* __restrict__ part,
                                                      const float* __restrict__ stats,
                                                      f16* __restrict__ ctx) {
    const int blk = blockIdx.x;
    const int b = blk >> 7, h = blk & 127;
    const int tid = threadIdx.x;
    float m[NSPLIT], l[NSPLIT];
    float M = -INFINITY;
#pragma unroll
    for (int s = 0; s < NSPLIT; ++s) {
        size_t sb = (((size_t)b * NSPLIT + s) * NH + h) * 2;
        m[s] = stats[sb]; l[s] = stats[sb + 1];
        M = fmaxf(M, m[s]);
    }
    float w[NSPLIT], denom = 0.f;
#pragma unroll
    for (int s = 0; s < NSPLIT; ++s) {
        w[s] = l[s] * exp2f((m[s] - M) * LOG2E);
        denom += w[s];
    }
    float inv = 1.0f / denom;
    f32x4 sum = f32x4{0.f, 0.f, 0.f, 0.f};
#pragma unroll
    for (int s = 0; s < NSPLIT; ++s) {
        f16x4 v = *(const f16x4*)&part[(((size_t)b * NSPLIT + s) * NH + h) * RR + tid * 4];
        sum.x += w[s] * (float)v.x; sum.y += w[s] * (float)v.y;
        sum.z += w[s] * (float)v.z; sum.w += w[s] * (float)v.w;
    }
    f16x4 o = {(f16)(sum.x * inv), (f16)(sum.y * inv), (f16)(sum.z * inv), (f16)(sum.w * inv)};
    *(f16x4*)&ctx[((size_t)b * NH + h) * RR + tid * 4] = o;
}

// ---------------- Kernel D: out[b,h,k] = sum_r w_vc[h,k,r]*ctx[b,h,r] (fp32 out) ----------------
// MFMA: m=b(32), n=k(64 half), K=r=512 fully staged. Grid 256 = (h, k-half).
__global__ __launch_bounds__(512) void outproj_kernel(const f16* __restrict__ ctx,
                                                      const float* __restrict__ w_vc,
                                                      float* __restrict__ out) {
    __shared__ f16 wv_s[64][520];    // [k_out][r] r-contiguous (B operand) — matches w_vc layout
    __shared__ f16 ctx_s[32][520];   // [b][r] (A operand)
    const int tid = threadIdx.x;
    const int lane = tid & 63, wave = tid >> 6;
    const int lh = lane & 15, quad = lane >> 4;
    const int h = blockIdx.x >> 1;
    const int kh = blockIdx.x & 1;
    {   // stage ctx 32 x 512 f16
        int bb = tid >> 4, sg = (tid & 15) * 32;
        const f16* src = &ctx[((size_t)bb * NH + h) * RR + sg];
#pragma unroll
        for (int k2 = 0; k2 < 4; ++k2)
            *(f16x8*)&ctx_s[bb][sg + k2 * 8] = *(const f16x8*)&src[k2 * 8];
    }
    {   // stage w_vc 64 x 512 fp32 -> f16
        int r = tid >> 3, sg = (tid & 7) * 64;
        const float* src = &w_vc[((size_t)h * HD + kh * 64 + r) * RR + sg];
#pragma unroll
        for (int u = 0; u < 8; ++u) {
            f32x4 v0 = *(const f32x4*)&src[u * 8], v1 = *(const f32x4*)&src[u * 8 + 4];
            f16x8 p = {(f16)v0.x,(f16)v0.y,(f16)v0.z,(f16)v0.w,(f16)v1.x,(f16)v1.y,(f16)v1.z,(f16)v1.w};
            *(f16x8*)&wv_s[r][sg + u * 8] = p;
        }
    }
    __syncthreads();
    const int mt = wave & 1, nt = wave >> 1;
    f32x4 acc = {0.f, 0.f, 0.f, 0.f};
#pragma unroll
    for (int kt = 0; kt < 16; ++kt) {
        f16x8 a = *(const f16x8*)&ctx_s[mt * 16 + lh][kt * 32 + quad * 8];
        f16x8 bb = *(const f16x8*)&wv_s[nt * 16 + lh][kt * 32 + quad * 8];
        acc = __builtin_amdgcn_mfma_f32_16x16x32_f16(a, bb, acc, 0, 0, 0);
    }
#pragma unroll
    for (int i = 0; i < 4; ++i)
        out[(size_t)(mt * 16 + quad * 4 + i) * (NH * HD) + h * HD + kh * 64 + nt * 16 + lh] = acc[i];
}

extern "C" void kernel_launch(void* const* d_in, const int* in_sizes, int n_in,
                              void* d_out, int out_size, void* d_ws, size_t ws_size,
                              hipStream_t stream) {
    const float* hidden = (const float*)d_in[0];
    const float* ckv    = (const float*)d_in[1];
    const float* Wq     = (const float*)d_in[2];
    const float* bq     = (const float*)d_in[3];
    const float* w_kc   = (const float*)d_in[4];
    const float* w_vc   = (const float*)d_in[5];
    float* out = (float*)d_out;

    char* ws = (char*)d_ws;
    f16*   q16   = (f16*)(ws);                        // 32*16384*2      = 1 MB
    f16*   qabs  = (f16*)(ws + (1u << 20));           // 32*128*512*2    = 4 MB
    f16*   part  = (f16*)(ws + 5u * (1u << 20));      // 32*8*128*512*2  = 32 MB
    float* stats = (float*)(ws + 37u * (1u << 20));   // 32*8*128*2*4    = 256 KB
    f16*   ctx   = (f16*)(ws + 38u * (1u << 20));     // 32*128*512*2    = 4 MB

    qproj_kernel<<<256, 512, 0, stream>>>(hidden, Wq, bq, q16);
    qabs_kernel<<<256, 512, 0, stream>>>(q16, w_kc, qabs);
    attn_kernel<<<256, 512, 0, stream>>>(ckv, qabs, part, stats);
    combine_kernel<<<BB * NH, 128, 0, stream>>>(part, stats, ctx);
    outproj_kernel<<<256, 512, 0, stream>>>(ctx, w_vc, out);
}